// Round 7
// baseline (272.106 us; speedup 1.0000x reference)
//
#include <hip/hip_runtime.h>

typedef _Float16 half8_t __attribute__((ext_vector_type(8)));
typedef _Float16 half4_t __attribute__((ext_vector_type(4)));
typedef float    float4_t __attribute__((ext_vector_type(4)));

// ---------------- ws layout ----------------
// [0, 59904)        wqkvP  f16  [288][104]  wqkvP[f][k] = W_qkv[k][f], cols 96..103 = 0 (pad)
// [59904, 78336)    woutT  f16  [96][96]    woutT[f][k] = W_out[k][f]
// [78336, 82432)    biasT  f32  [4][16][16] biasT[m][j][i] = bias_variant_m[i][j]
#define WP_STRIDE 104
#define WOUTT_OFF_H 29952   // in f16 elements
#define BIAST_OFF_B 78336   // bytes

__global__ void prep_kernel(const float* __restrict__ Wqkv,
                            const float* __restrict__ Wout,
                            const float* __restrict__ pos,
                            _Float16* __restrict__ wqkvP,
                            _Float16* __restrict__ woutT,
                            float* __restrict__ biasT) {
  int idx = blockIdx.x * 256 + threadIdx.x;
  if (idx < 288 * 104) {
    int f = idx / 104, c = idx % 104;
    wqkvP[idx] = (c < 96) ? (_Float16)Wqkv[c * 288 + f] : (_Float16)0.f;
  } else if (idx < 288 * 104 + 96 * 96) {
    int t = idx - 288 * 104;
    int f = t / 96, k = t % 96;
    woutT[t] = (_Float16)Wout[k * 96 + f];
  } else if (idx < 288 * 104 + 96 * 96 + 1024) {
    int t = idx - (288 * 104 + 96 * 96);
    int m = t >> 8, j = (t >> 4) & 15, i = t & 15;   // store [j][i] = bias[i][j]
    int xi = i >> 2, yi = i & 3, xj = j >> 2, yj = j & 3;
    // bias[i][j] = pos[idx[j] - idx[i] + 3]  (key minus query)
    float v = pos[(xj - xi + 3) * 7 + (yj - yi + 3)];
    if ((m & 1) && ((i >= 8) != (j >= 8))) v -= 1e9f;      // ul mask (last window row)
    if ((m & 2) && ((yi >= 2) != (yj >= 2))) v -= 1e9f;    // lr mask (last window col)
    biasT[t] = v;
  }
}

static __device__ __forceinline__ half4_t pack4(float4_t a) {
  half4_t h;
  h[0] = (_Float16)a[0]; h[1] = (_Float16)a[1];
  h[2] = (_Float16)a[2]; h[3] = (_Float16)a[3];
  return h;
}

static __device__ __forceinline__ void gload_lds16(const void* g, void* l) {
  __builtin_amdgcn_global_load_lds(
      (const __attribute__((address_space(1))) unsigned int*)g,
      (__attribute__((address_space(3))) unsigned int*)l, 16, 0, 0);
}

// 4 waves/block; only q,k weight rows in LDS (39936 B -> 4 blocks/CU = 4 waves/SIMD);
// v-weights + Wout fragments hoisted in registers; all intermediates register-resident
// via direct MFMA D->A/B fragment chaining. Softmax without max-subtract (safe: diagonal
// never masked, |logit| << 88; masked = -1e9 -> exp = 0 exactly).
__global__ __launch_bounds__(256, 4)
void swin_fused(const float* __restrict__ x,
                const _Float16* __restrict__ wqkvP,
                const _Float16* __restrict__ woutT,
                const float* __restrict__ biasT,
                const float* __restrict__ b_out,
                float* __restrict__ out) {
  __shared__ _Float16 wlds[192 * WP_STRIDE];   // 39936 B
  const int tid  = threadIdx.x;
  const int wave = tid >> 6;
  const int lane = tid & 63;
  const int l15  = lane & 15;
  const int g    = lane >> 4;
  const int ty = l15 >> 2, tx = l15 & 3;

  const int blk   = blockIdx.x;
  const int batch = blk / 49;
  const int wbase = (blk % 49) * 16 + wave * 4;   // this wave's 4 windows

  // per-window token positions (cyclic shift folded in; reused for stores)
  int pp[4], qq[4];
#pragma unroll
  for (int w = 0; w < 4; ++w) {
    int wid = wbase + w;
    int wrow = wid / 28, wcol = wid % 28;
    int p = wrow * 4 + ty + 2; if (p >= 112) p -= 112;
    int q = wcol * 4 + tx + 2; if (q >= 112) q -= 112;
    pp[w] = p; qq[w] = q;
  }

  // ---- issue all x loads first
  float4_t xa[4][3], xb[4][3];
#pragma unroll
  for (int w = 0; w < 4; ++w) {
    const float* xr = x + (((size_t)batch * 112 + pp[w]) * 112 + qq[w]) * 96 + g * 8;
#pragma unroll
    for (int kt = 0; kt < 3; ++kt) {
      xa[w][kt] = *(const float4_t*)(xr + kt * 32);
      xb[w][kt] = *(const float4_t*)(xr + kt * 32 + 4);
    }
  }

  // ---- async stage q,k weight rows (rows 0..191 of wqkvP, linear copy, 2496 chunks)
  {
    const char* gs = (const char*)wqkvP;
    char* lb = (char*)wlds;
#pragma unroll
    for (int k = 0; k < 10; ++k) {
      int cb = k * 256 + wave * 64;          // wave-uniform chunk base
      if (cb < 2496) {
        size_t off = (size_t)(cb + lane) * 16;
        gload_lds16(gs + off, lb + off);
      }
    }
  }

  // ---- hoist v-weight fragments (B of x@Wv): col=vfeat l15, k=8g..; rows 192..287
  half8_t vwf[6][3];
#pragma unroll
  for (int f6 = 0; f6 < 6; ++f6)
#pragma unroll
    for (int kt = 0; kt < 3; ++kt)
      vwf[f6][kt] = *(const half8_t*)&wqkvP[(192 + f6 * 16 + l15) * WP_STRIDE + kt * 32 + g * 8];

  // ---- hoist WoutT fragments (A of GEMM3): row=outfeat mt*16+l15, k=kt*16+4g..
  half4_t woutf[6][6];
#pragma unroll
  for (int mt = 0; mt < 6; ++mt)
#pragma unroll
    for (int kt = 0; kt < 6; ++kt)
      woutf[mt][kt] = *(const half4_t*)&woutT[(mt * 16 + l15) * 96 + kt * 16 + g * 4];

  // ---- bias (per window variant) + output bias, hoisted
  float bb0[4], bb1[4], bb2[4], bb3[4];
#pragma unroll
  for (int w = 0; w < 4; ++w) {
    int wid = wbase + w;
    int var = ((wid / 28) == 27 ? 1 : 0) + ((wid % 28) == 27 ? 2 : 0);
    const float* bt = biasT + var * 256 + g * 64 + l15;   // [var][j=4g+r][i=l15]
    bb0[w] = bt[0]; bb1[w] = bt[16]; bb2[w] = bt[32]; bb3[w] = bt[48];
  }
  float4_t obias[6];
#pragma unroll
  for (int mt = 0; mt < 6; ++mt)
    obias[mt] = *(const float4_t*)&b_out[mt * 16 + g * 4];

  // ---- convert x to f16 fragments
  half8_t xf[4][3];
#pragma unroll
  for (int w = 0; w < 4; ++w)
#pragma unroll
    for (int kt = 0; kt < 3; ++kt) {
      half8_t h;
      h[0] = (_Float16)xa[w][kt][0]; h[1] = (_Float16)xa[w][kt][1];
      h[2] = (_Float16)xa[w][kt][2]; h[3] = (_Float16)xa[w][kt][3];
      h[4] = (_Float16)xb[w][kt][0]; h[5] = (_Float16)xb[w][kt][1];
      h[6] = (_Float16)xb[w][kt][2]; h[7] = (_Float16)xb[w][kt][3];
      xf[w][kt] = h;
    }

  __syncthreads();   // staging complete (drains vmcnt incl. global_load_lds)

  const float scale = 0.17677669529663687f;  // 32^-0.5

  // ---- per-window compute, all intermediates in registers
#pragma unroll
  for (int w = 0; w < 4; ++w) {
    // GEMM1 q,k tiles: D = Wqk_slice @ x^T (per-lane: col=tok l15, feats 4g+r)
    half4_t qk16[12];
#pragma unroll
    for (int f = 0; f < 12; ++f) {
      const _Float16* wp = &wlds[(f * 16 + l15) * WP_STRIDE + g * 8];
      half8_t w0 = *(const half8_t*)(wp);
      half8_t w1 = *(const half8_t*)(wp + 32);
      half8_t w2 = *(const half8_t*)(wp + 64);
      float4_t acc = {0.f, 0.f, 0.f, 0.f};
      acc = __builtin_amdgcn_mfma_f32_16x16x32_f16(w0, xf[w][0], acc, 0, 0, 0);
      acc = __builtin_amdgcn_mfma_f32_16x16x32_f16(w1, xf[w][1], acc, 0, 0, 0);
      acc = __builtin_amdgcn_mfma_f32_16x16x32_f16(w2, xf[w][2], acc, 0, 0, 0);
      qk16[f] = pack4(acc);
    }
    // GEMM1 v tiles: D = x @ Wv_slice (per-lane: col=vfeat l15, toks 4g+r); reg-only
    half4_t vt16[6];
#pragma unroll
    for (int f6 = 0; f6 < 6; ++f6) {
      float4_t acc = {0.f, 0.f, 0.f, 0.f};
      acc = __builtin_amdgcn_mfma_f32_16x16x32_f16(xf[w][0], vwf[f6][0], acc, 0, 0, 0);
      acc = __builtin_amdgcn_mfma_f32_16x16x32_f16(xf[w][1], vwf[f6][1], acc, 0, 0, 0);
      acc = __builtin_amdgcn_mfma_f32_16x16x32_f16(xf[w][2], vwf[f6][2], acc, 0, 0, 0);
      vt16[f6] = pack4(acc);
    }

    // attention: QK^T + exp (no max-subtract), batched cross-lane sum for 3 heads
    float ps[3][4], ss[3];
#pragma unroll
    for (int h = 0; h < 3; ++h) {
      float4_t dd = {0.f, 0.f, 0.f, 0.f};
      dd = __builtin_amdgcn_mfma_f32_16x16x16f16(qk16[6 + 2 * h], qk16[2 * h],     dd, 0, 0, 0);
      dd = __builtin_amdgcn_mfma_f32_16x16x16f16(qk16[7 + 2 * h], qk16[2 * h + 1], dd, 0, 0, 0);
      ps[h][0] = __expf(fmaf(dd[0], scale, bb0[w]));
      ps[h][1] = __expf(fmaf(dd[1], scale, bb1[w]));
      ps[h][2] = __expf(fmaf(dd[2], scale, bb2[w]));
      ps[h][3] = __expf(fmaf(dd[3], scale, bb3[w]));
      ss[h] = (ps[h][0] + ps[h][1]) + (ps[h][2] + ps[h][3]);
    }
    ss[0] += __shfl_xor(ss[0], 16, 64);
    ss[1] += __shfl_xor(ss[1], 16, 64);
    ss[2] += __shfl_xor(ss[2], 16, 64);
    ss[0] += __shfl_xor(ss[0], 32, 64);
    ss[1] += __shfl_xor(ss[1], 32, 64);
    ss[2] += __shfl_xor(ss[2], 32, 64);

    half4_t ao[6];
#pragma unroll
    for (int h = 0; h < 3; ++h) {
      float r = __builtin_amdgcn_rcpf(ss[h]);
      half4_t pb;   // P^T: B operand (col=query l15, k=key 4g+r)
      pb[0] = (_Float16)(ps[h][0] * r); pb[1] = (_Float16)(ps[h][1] * r);
      pb[2] = (_Float16)(ps[h][2] * r); pb[3] = (_Float16)(ps[h][3] * r);
      float4_t o0 = {0.f, 0.f, 0.f, 0.f};
      o0 = __builtin_amdgcn_mfma_f32_16x16x16f16(vt16[2 * h], pb, o0, 0, 0, 0);
      ao[2 * h] = pack4(o0);
      float4_t o1 = {0.f, 0.f, 0.f, 0.f};
      o1 = __builtin_amdgcn_mfma_f32_16x16x16f16(vt16[2 * h + 1], pb, o1, 0, 0, 0);
      ao[2 * h + 1] = pack4(o1);
    }

    // GEMM3: y^T = WoutT @ ao^T (A hoisted, B = ao direct); store with inverse roll
    float* orow = out + (((size_t)batch * 112 + pp[w]) * 112 + qq[w]) * 96;
#pragma unroll
    for (int mt = 0; mt < 6; ++mt) {
      float4_t acc = {0.f, 0.f, 0.f, 0.f};
#pragma unroll
      for (int kt = 0; kt < 6; ++kt)
        acc = __builtin_amdgcn_mfma_f32_16x16x16f16(woutf[mt][kt], ao[kt], acc, 0, 0, 0);
      acc[0] += obias[mt][0]; acc[1] += obias[mt][1];
      acc[2] += obias[mt][2]; acc[3] += obias[mt][3];
      *(float4_t*)&orow[mt * 16 + g * 4] = acc;
    }
  }
}

extern "C" void kernel_launch(void* const* d_in, const int* in_sizes, int n_in,
                              void* d_out, int out_size, void* d_ws, size_t ws_size,
                              hipStream_t stream) {
  const float* x    = (const float*)d_in[0];
  const float* Wqkv = (const float*)d_in[1];
  const float* pos  = (const float*)d_in[2];
  const float* Wout = (const float*)d_in[3];
  const float* bout = (const float*)d_in[4];
  char* ws = (char*)d_ws;
  _Float16* wqkvP = (_Float16*)ws;
  _Float16* woutT = ((_Float16*)ws) + WOUTT_OFF_H;
  float* biasT = (float*)(ws + BIAST_OFF_B);

  prep_kernel<<<157, 256, 0, stream>>>(Wqkv, Wout, pos, wqkvP, woutT, biasT);
  swin_fused<<<1568, 256, 0, stream>>>(x, wqkvP, woutT, biasT, bout, (float*)d_out);
}

// Round 8
// 112.346 us; speedup vs baseline: 2.4220x; 2.4220x over previous
//
#include <hip/hip_runtime.h>

typedef _Float16 half8_t __attribute__((ext_vector_type(8)));
typedef _Float16 half4_t __attribute__((ext_vector_type(4)));
typedef float    float4_t __attribute__((ext_vector_type(4)));

// ---------------- ws layout (f16 elements unless noted) ----------------
// [0, 19968)        wqkvP  [192][104]  q,k weight rows, cols 96..103 = 0 pad
//                   (wqkvP[f][c] = W_qkv[c][f], f = qk feature)
// [19968, 29184)    vB     fragment-order v-weights:
//                   vB[((f6*3+kt)*64 + lane)*8 + j] = W_qkv[(kt*32+(lane>>4)*8+j)*288 + 192+f6*16+(lane&15)]
// [29184, 38400)    woutB  fragment-order Wout (kt-pairs):
//                   woutB[((mt*3+kp)*64 + lane)*8 + s] = W_out[((2*kp+(s>>2))*16+(lane>>4)*4+(s&3))*96 + mt*16+(lane&15)]
// [38400 f16 = 76800 B, 80896 B)  biasT f32 [4][16][16]: biasT[m][j][i] = bias_m[i][j]
#define WP_STRIDE 104
#define VB_OFF 19968
#define WOUTB_OFF 29184
#define BIAST_OFF_B 76800

__global__ void prep_kernel(const float* __restrict__ Wqkv,
                            const float* __restrict__ Wout,
                            const float* __restrict__ pos,
                            _Float16* __restrict__ wsh,
                            float* __restrict__ biasT) {
  int idx = blockIdx.x * 256 + threadIdx.x;
  if (idx < 19968) {
    int f = idx / 104, c = idx % 104;
    wsh[idx] = (c < 96) ? (_Float16)Wqkv[c * 288 + f] : (_Float16)0.f;
  } else if (idx < 29184) {
    int t = idx - VB_OFF;
    int j = t & 7, lane = (t >> 3) & 63, fk = t >> 9;      // fk in [0,18)
    int f6 = fk / 3, kt = fk % 3;
    int l15 = lane & 15, g = lane >> 4;
    int k = kt * 32 + g * 8 + j;                            // input feature
    int f = 192 + f6 * 16 + l15;                            // v output feature row
    wsh[idx] = (_Float16)Wqkv[k * 288 + f];
  } else if (idx < 38400) {
    int t = idx - WOUTB_OFF;
    int s = t & 7, lane = (t >> 3) & 63, fk = t >> 9;       // fk in [0,18)
    int mt = fk / 3, kp = fk % 3;
    int l15 = lane & 15, g = lane >> 4;
    int kt = kp * 2 + (s >> 2), j = s & 3;
    int k = kt * 16 + g * 4 + j;                            // attn feature
    int f = mt * 16 + l15;                                  // out feature
    wsh[idx] = (_Float16)Wout[k * 96 + f];
  } else if (idx < 38400 + 1024) {
    int t = idx - 38400;
    int m = t >> 8, j = (t >> 4) & 15, i = t & 15;          // store [j][i] = bias[i][j]
    int xi = i >> 2, yi = i & 3, xj = j >> 2, yj = j & 3;
    float v = pos[(xj - xi + 3) * 7 + (yj - yi + 3)];       // key minus query
    if ((m & 1) && ((i >= 8) != (j >= 8))) v -= 1e9f;       // ul mask (last window row)
    if ((m & 2) && ((yi >= 2) != (yj >= 2))) v -= 1e9f;     // lr mask (last window col)
    biasT[t] = v;
  }
}

static __device__ __forceinline__ half4_t pack4(float4_t a) {
  half4_t h;
  h[0] = (_Float16)a[0]; h[1] = (_Float16)a[1];
  h[2] = (_Float16)a[2]; h[3] = (_Float16)a[3];
  return h;
}

static __device__ __forceinline__ void gload_lds16(const void* g, void* l) {
  __builtin_amdgcn_global_load_lds(
      (const __attribute__((address_space(1))) unsigned int*)g,
      (__attribute__((address_space(3))) unsigned int*)l, 16, 0, 0);
}

// 4 waves/block, 2 windows/wave. q,k weights in LDS (39936 B, async-staged);
// v / Wout weights read per-window as pre-swizzled fragment-order coalesced b128
// loads (L1-resident, no persistent VGPRs). All intermediates register-chained.
// launch_bounds(256,3): VGPR cap 170 — counted demand ~150, no spill.
__global__ __launch_bounds__(256, 3)
void swin_fused(const float* __restrict__ x,
                const _Float16* __restrict__ wsh,
                const float* __restrict__ biasT,
                const float* __restrict__ b_out,
                float* __restrict__ out) {
  __shared__ _Float16 wlds[192 * WP_STRIDE];   // 39936 B
  const int tid  = threadIdx.x;
  const int wave = tid >> 6;
  const int lane = tid & 63;
  const int l15  = lane & 15;
  const int g    = lane >> 4;
  const int ty = l15 >> 2, tx = l15 & 3;

  const int blk   = blockIdx.x;
  const int batch = blk / 98;
  const int wbase = (blk % 98) * 8 + wave * 2;   // this wave's 2 windows

  // per-window token positions (cyclic shift folded in; reused for stores)
  int pp[2], qq[2];
#pragma unroll
  for (int w = 0; w < 2; ++w) {
    int wid = wbase + w;
    int wrow = wid / 28, wcol = wid % 28;
    int p = wrow * 4 + ty + 2; if (p >= 112) p -= 112;
    int q = wcol * 4 + tx + 2; if (q >= 112) q -= 112;
    pp[w] = p; qq[w] = q;
  }

  // ---- issue x loads
  float4_t xa[2][3], xb[2][3];
#pragma unroll
  for (int w = 0; w < 2; ++w) {
    const float* xr = x + (((size_t)batch * 112 + pp[w]) * 112 + qq[w]) * 96 + g * 8;
#pragma unroll
    for (int kt = 0; kt < 3; ++kt) {
      xa[w][kt] = *(const float4_t*)(xr + kt * 32);
      xb[w][kt] = *(const float4_t*)(xr + kt * 32 + 4);
    }
  }

  // ---- async stage q,k weight rows (linear copy: 2496 16B chunks)
  {
    const char* gs = (const char*)wsh;
    char* lb = (char*)wlds;
#pragma unroll
    for (int k = 0; k < 10; ++k) {
      int cb = k * 256 + wave * 64;          // wave-uniform chunk base
      if (cb < 2496) {
        size_t off = (size_t)(cb + lane) * 16;
        gload_lds16(gs + off, lb + off);
      }
    }
  }

  // ---- per-window bias values
  float bb0[2], bb1[2], bb2[2], bb3[2];
#pragma unroll
  for (int w = 0; w < 2; ++w) {
    int wid = wbase + w;
    int var = ((wid / 28) == 27 ? 1 : 0) + ((wid % 28) == 27 ? 2 : 0);
    const float* bt = biasT + var * 256 + g * 64 + l15;   // [var][j=4g+r][i=l15]
    bb0[w] = bt[0]; bb1[w] = bt[16]; bb2[w] = bt[32]; bb3[w] = bt[48];
  }

  // ---- convert x to f16 fragments
  half8_t xf[2][3];
#pragma unroll
  for (int w = 0; w < 2; ++w)
#pragma unroll
    for (int kt = 0; kt < 3; ++kt) {
      half8_t h;
      h[0] = (_Float16)xa[w][kt][0]; h[1] = (_Float16)xa[w][kt][1];
      h[2] = (_Float16)xa[w][kt][2]; h[3] = (_Float16)xa[w][kt][3];
      h[4] = (_Float16)xb[w][kt][0]; h[5] = (_Float16)xb[w][kt][1];
      h[6] = (_Float16)xb[w][kt][2]; h[7] = (_Float16)xb[w][kt][3];
      xf[w][kt] = h;
    }

  __syncthreads();   // staging complete (barrier drains vmcnt incl. global_load_lds)

  const _Float16* vB    = wsh + VB_OFF;
  const _Float16* woutB = wsh + WOUTB_OFF;
  const float scale = 0.17677669529663687f;  // 32^-0.5

  // ---- per-window compute, intermediates register-chained
#pragma unroll
  for (int w = 0; w < 2; ++w) {
    // GEMM1 q,k tiles: D = Wqk_slice @ x^T (per-lane: col=tok l15, feats 4g+r)
    half4_t qk16[12];
#pragma unroll
    for (int f = 0; f < 12; ++f) {
      const _Float16* wp = &wlds[(f * 16 + l15) * WP_STRIDE + g * 8];
      half8_t w0 = *(const half8_t*)(wp);
      half8_t w1 = *(const half8_t*)(wp + 32);
      half8_t w2 = *(const half8_t*)(wp + 64);
      float4_t acc = {0.f, 0.f, 0.f, 0.f};
      acc = __builtin_amdgcn_mfma_f32_16x16x32_f16(w0, xf[w][0], acc, 0, 0, 0);
      acc = __builtin_amdgcn_mfma_f32_16x16x32_f16(w1, xf[w][1], acc, 0, 0, 0);
      acc = __builtin_amdgcn_mfma_f32_16x16x32_f16(w2, xf[w][2], acc, 0, 0, 0);
      qk16[f] = pack4(acc);
    }
    // GEMM1 v tiles: D = x @ Wv_slice; B-frags are coalesced b128 loads (L1)
    half4_t vt16[6];
#pragma unroll
    for (int f6 = 0; f6 < 6; ++f6) {
      float4_t acc = {0.f, 0.f, 0.f, 0.f};
#pragma unroll
      for (int kt = 0; kt < 3; ++kt) {
        half8_t vb = *(const half8_t*)&vB[((f6 * 3 + kt) * 64 + lane) * 8];
        acc = __builtin_amdgcn_mfma_f32_16x16x32_f16(xf[w][kt], vb, acc, 0, 0, 0);
      }
      vt16[f6] = pack4(acc);
    }

    // attention: QK^T + exp (no max-subtract; masked = -1e9 -> exp 0), batched shuffles
    float ps[3][4], ss[3];
#pragma unroll
    for (int h = 0; h < 3; ++h) {
      float4_t dd = {0.f, 0.f, 0.f, 0.f};
      dd = __builtin_amdgcn_mfma_f32_16x16x16f16(qk16[6 + 2 * h], qk16[2 * h],     dd, 0, 0, 0);
      dd = __builtin_amdgcn_mfma_f32_16x16x16f16(qk16[7 + 2 * h], qk16[2 * h + 1], dd, 0, 0, 0);
      ps[h][0] = __expf(fmaf(dd[0], scale, bb0[w]));
      ps[h][1] = __expf(fmaf(dd[1], scale, bb1[w]));
      ps[h][2] = __expf(fmaf(dd[2], scale, bb2[w]));
      ps[h][3] = __expf(fmaf(dd[3], scale, bb3[w]));
      ss[h] = (ps[h][0] + ps[h][1]) + (ps[h][2] + ps[h][3]);
    }
    ss[0] += __shfl_xor(ss[0], 16, 64);
    ss[1] += __shfl_xor(ss[1], 16, 64);
    ss[2] += __shfl_xor(ss[2], 16, 64);
    ss[0] += __shfl_xor(ss[0], 32, 64);
    ss[1] += __shfl_xor(ss[1], 32, 64);
    ss[2] += __shfl_xor(ss[2], 32, 64);

    half4_t ao[6];
#pragma unroll
    for (int h = 0; h < 3; ++h) {
      float r = __builtin_amdgcn_rcpf(ss[h]);
      half4_t pb;   // P^T: B operand (col=query l15, k=key 4g+r)
      pb[0] = (_Float16)(ps[h][0] * r); pb[1] = (_Float16)(ps[h][1] * r);
      pb[2] = (_Float16)(ps[h][2] * r); pb[3] = (_Float16)(ps[h][3] * r);
      float4_t o0 = {0.f, 0.f, 0.f, 0.f};
      o0 = __builtin_amdgcn_mfma_f32_16x16x16f16(vt16[2 * h], pb, o0, 0, 0, 0);
      ao[2 * h] = pack4(o0);
      float4_t o1 = {0.f, 0.f, 0.f, 0.f};
      o1 = __builtin_amdgcn_mfma_f32_16x16x16f16(vt16[2 * h + 1], pb, o1, 0, 0, 0);
      ao[2 * h + 1] = pack4(o1);
    }

    // GEMM3: y^T = Wout^T @ ao^T; A-frags as coalesced b128 kt-pair loads (L1)
    float* orow = out + (((size_t)batch * 112 + pp[w]) * 112 + qq[w]) * 96;
#pragma unroll
    for (int mt = 0; mt < 6; ++mt) {
      float4_t acc = {0.f, 0.f, 0.f, 0.f};
#pragma unroll
      for (int kp = 0; kp < 3; ++kp) {
        half8_t wp = *(const half8_t*)&woutB[((mt * 3 + kp) * 64 + lane) * 8];
        half4_t lo = __builtin_shufflevector(wp, wp, 0, 1, 2, 3);
        half4_t hi = __builtin_shufflevector(wp, wp, 4, 5, 6, 7);
        acc = __builtin_amdgcn_mfma_f32_16x16x16f16(lo, ao[2 * kp],     acc, 0, 0, 0);
        acc = __builtin_amdgcn_mfma_f32_16x16x16f16(hi, ao[2 * kp + 1], acc, 0, 0, 0);
      }
      float4_t bb = *(const float4_t*)&b_out[mt * 16 + g * 4];
      acc[0] += bb[0]; acc[1] += bb[1]; acc[2] += bb[2]; acc[3] += bb[3];
      *(float4_t*)&orow[mt * 16 + g * 4] = acc;
    }
  }
}

extern "C" void kernel_launch(void* const* d_in, const int* in_sizes, int n_in,
                              void* d_out, int out_size, void* d_ws, size_t ws_size,
                              hipStream_t stream) {
  const float* x    = (const float*)d_in[0];
  const float* Wqkv = (const float*)d_in[1];
  const float* pos  = (const float*)d_in[2];
  const float* Wout = (const float*)d_in[3];
  const float* bout = (const float*)d_in[4];
  char* ws = (char*)d_ws;
  _Float16* wsh  = (_Float16*)ws;
  float* biasT = (float*)(ws + BIAST_OFF_B);

  prep_kernel<<<154, 256, 0, stream>>>(Wqkv, Wout, pos, wsh, biasT);
  swin_fused<<<3136, 256, 0, stream>>>(x, wsh, biasT, bout, (float*)d_out);
}